// Round 1
// baseline (1514.448 us; speedup 1.0000x reference)
//
#include <hip/hip_runtime.h>

// ---------------------------------------------------------------------------
// Problem geometry
// ---------------------------------------------------------------------------
constexpr int NB = 16, NC = 64, NH = 128, NW = 128;
constexpr int NPIX = NH * NW;          // 16384
constexpr int NTOT = NB * NPIX;        // 262144 pixels
constexpr size_t BUF = (size_t)NTOT * NC;  // 16,777,216 floats = 64 MB

// ws layout (float offsets)
constexpr size_t OFF_A   = 0;                    // x channels-last (pristine)
constexpr size_t OFF_ACT = BUF;                  // running activation
constexpr size_t OFF_V   = 2 * BUF;              // v, later lr2
constexpr size_t OFF_S   = 3 * BUF;              // [2][16][8][8][8] = 16384
constexpr size_t OFF_QSQ = OFF_S   + 2*16*512;   // [2][16][64] = 2048
constexpr size_t OFF_KSQ = OFF_QSQ + 2048;       // 2048
constexpr size_t OFF_BN1 = OFF_KSQ + 2048;       // sum[64], sumsq[64]
constexpr size_t OFF_BN2 = OFF_BN1 + 128;        // 128
constexpr size_t ZERO_FLOATS = 16384 + 2048 + 2048 + 128 + 128; // 20736
constexpr size_t OFF_W2  = OFF_BN2 + 128;        // [2][16][64][64] = 131072
constexpr size_t OFF_AB1 = OFF_W2  + 131072;     // a1[64], b1[64]
constexpr size_t OFF_AB2 = OFF_AB1 + 128;        // a2[64], b2[64]
constexpr size_t OFF_Y   = OFF_AB2 + 128;        // [16][64][64] = 65536
constexpr size_t OFF_GATE= OFF_Y   + 65536;      // [16][64]

__device__ __forceinline__ float leaky(float x) { return x >= 0.f ? x : 0.2f * x; }

// ---------------------------------------------------------------------------
// k0: NCHW -> channels-last (BHWC)
// ---------------------------------------------------------------------------
__global__ __launch_bounds__(256) void k_transpose_in(const float* __restrict__ x,
                                                      float* __restrict__ A) {
  __shared__ float t[64][65];
  int blk = blockIdx.x;            // b*256 + seg
  int b = blk >> 8;
  int p0 = (blk & 255) * 64;
  int tid = threadIdx.x;
  int cq = tid >> 6, p = tid & 63;
  for (int i = 0; i < 16; i++) {
    int c = cq * 16 + i;
    t[p][c] = x[((size_t)(b * 64 + c)) * NPIX + p0 + p];
  }
  __syncthreads();
  int pq = tid >> 6, c = tid & 63;
  for (int i = 0; i < 16; i++) {
    int p2 = pq * 16 + i;
    A[((size_t)(b * NPIX + p0 + p2)) * 64 + c] = t[p2][c];
  }
}

// ---------------------------------------------------------------------------
// k1: v = act @ wv   (thread-per-pixel, weights via uniform scalar loads)
// ---------------------------------------------------------------------------
__global__ __launch_bounds__(256) void k_mat_v(const float* __restrict__ act,
                                               const float* __restrict__ wv,
                                               float* __restrict__ v, int l) {
  int gpix = blockIdx.x * 256 + threadIdx.x;
  const float* xr = act + (size_t)gpix * 64;
  const float* W = wv + (size_t)l * 4096;
  float* out = v + (size_t)gpix * 64;
#pragma unroll 1
  for (int jc = 0; jc < 4; jc++) {
    float acc[16];
#pragma unroll
    for (int j = 0; j < 16; j++) acc[j] = 0.f;
#pragma unroll 1
    for (int cc = 0; cc < 4; cc++) {
      const float4 x0 = *(const float4*)(xr + cc * 16);
      const float4 x1 = *(const float4*)(xr + cc * 16 + 4);
      const float4 x2 = *(const float4*)(xr + cc * 16 + 8);
      const float4 x3 = *(const float4*)(xr + cc * 16 + 12);
      const float xv[16] = {x0.x,x0.y,x0.z,x0.w, x1.x,x1.y,x1.z,x1.w,
                            x2.x,x2.y,x2.z,x2.w, x3.x,x3.y,x3.z,x3.w};
#pragma unroll
      for (int ci = 0; ci < 16; ci++) {
        const float* wrow = W + (cc * 16 + ci) * 64 + jc * 16;
#pragma unroll
        for (int j = 0; j < 16; j++) acc[j] = fmaf(xv[ci], wrow[j], acc[j]);
      }
    }
    float4 o0 = {acc[0], acc[1], acc[2], acc[3]};
    float4 o1 = {acc[4], acc[5], acc[6], acc[7]};
    float4 o2 = {acc[8], acc[9], acc[10], acc[11]};
    float4 o3 = {acc[12], acc[13], acc[14], acc[15]};
    *(float4*)(out + jc * 16)      = o0;
    *(float4*)(out + jc * 16 + 4)  = o1;
    *(float4*)(out + jc * 16 + 8)  = o2;
    *(float4*)(out + jc * 16 + 12) = o3;
  }
}

// ---------------------------------------------------------------------------
// k1b: on-the-fly q,k; accumulate S[b,h,d,e], sum q^2, sum k^2.
// One wave per image row; lane == channel (= h*8+d).
// ---------------------------------------------------------------------------
__global__ __launch_bounds__(256) void k_qk_stats(const float* __restrict__ act,
    const float* __restrict__ wq, const float* __restrict__ wk,
    float* __restrict__ S, float* __restrict__ qsq, float* __restrict__ ksq, int l) {
  int wave = (blockIdx.x * 256 + threadIdx.x) >> 6;  // 0..2047 (global row)
  int lane = threadIdx.x & 63;
  int b = wave >> 7, hh = wave & 127;
  const float* Wq = wq + (size_t)l * 4096;
  const float* Wk = wk + (size_t)l * 4096;
  float wqc[64], wkc[64];
#pragma unroll
  for (int ci = 0; ci < 64; ci++) {
    wqc[ci] = Wq[ci * 64 + lane];
    wkc[ci] = Wk[ci * 64 + lane];
  }
  float Sacc[8];
#pragma unroll
  for (int e = 0; e < 8; e++) Sacc[e] = 0.f;
  float qsa = 0.f, ksa = 0.f;
  int gbase = lane & 56;  // head-group base lane
  const float* rowp = act + ((size_t)(b * NPIX + hh * NW)) * 64;
#pragma unroll 1
  for (int w = 0; w < 128; w++) {
    const float* xp = rowp + w * 64;  // wave-uniform address
    float q = 0.f, k = 0.f;
#pragma unroll
    for (int ci = 0; ci < 64; ci++) {
      float xv = xp[ci];
      q = fmaf(xv, wqc[ci], q);
      k = fmaf(xv, wkc[ci], k);
    }
    qsa = fmaf(q, q, qsa);
    ksa = fmaf(k, k, ksa);
#pragma unroll
    for (int e = 0; e < 8; e++) {
      float qe = __shfl(q, gbase + e, 64);
      Sacc[e] = fmaf(k, qe, Sacc[e]);
    }
  }
  float* Sb = S + ((size_t)l * 16 + b) * 512 + lane * 8;  // lane = h*8+d
#pragma unroll
  for (int e = 0; e < 8; e++) atomicAdd(Sb + e, Sacc[e]);
  atomicAdd(qsq + ((size_t)l * 16 + b) * 64 + lane, qsa);
  atomicAdd(ksq + ((size_t)l * 16 + b) * 64 + lane, ksa);
}

// ---------------------------------------------------------------------------
// k2: per-batch attention softmax (8x8 per head) -> fold with wproj into W2
// ---------------------------------------------------------------------------
__global__ __launch_bounds__(64) void k_attn(const float* __restrict__ S,
    const float* __restrict__ qsq, const float* __restrict__ ksq,
    const float* __restrict__ wproj, float* __restrict__ W2, int l) {
  int b = blockIdx.x, t = threadIdx.x;
  __shared__ float A[8][8][8];  // [h][d][e]
  const float* Sb = S + ((size_t)l * 16 + b) * 512;
  const float* qs = qsq + ((size_t)l * 16 + b) * 64;
  const float* ks = ksq + ((size_t)l * 16 + b) * 64;
  int h = t >> 3, d = t & 7;
  float kden = fmaxf(sqrtf(ks[h * 8 + d]), 1e-12f);
  float pre[8];
  float mx = -1e30f;
#pragma unroll
  for (int e = 0; e < 8; e++) {
    float qden = fmaxf(sqrtf(qs[h * 8 + e]), 1e-12f);
    pre[e] = Sb[(h * 8 + d) * 8 + e] / (kden * qden);
    mx = fmaxf(mx, pre[e]);
  }
  float sum = 0.f;
#pragma unroll
  for (int e = 0; e < 8; e++) { pre[e] = expf(pre[e] - mx); sum += pre[e]; }
  float inv = 1.f / sum;
#pragma unroll
  for (int e = 0; e < 8; e++) A[h][d][e] = pre[e] * inv;
  __syncthreads();
  int co = t;
  const float* wp = wproj + (size_t)l * 4096;
  float* W2b = W2 + ((size_t)l * 16 + b) * 4096;
#pragma unroll 1
  for (int cin = 0; cin < 64; cin++) {
    int hh2 = cin >> 3, e = cin & 7;
    float acc = 0.f;
#pragma unroll
    for (int dd = 0; dd < 8; dd++)
      acc = fmaf(A[hh2][dd][e], wp[(hh2 * 8 + dd) * 64 + co], acc);
    W2b[cin * 64 + co] = acc;
  }
}

// ---------------------------------------------------------------------------
// k3: out = (v@W2 + bproj) * dw3x3(v) + act ; then LN -> @wff -> +residual
// 128 threads (one pixel each); per-pixel y row staged in LDS [128][65].
// ---------------------------------------------------------------------------
__global__ __launch_bounds__(128) void k_attnout_ff(
    const float* __restrict__ v, const float* __restrict__ actin,
    float* __restrict__ actout, const float* __restrict__ W2all,
    const float* __restrict__ bproj, const float* __restrict__ wpos,
    const float* __restrict__ lng, const float* __restrict__ lnb,
    const float* __restrict__ wff, int l) {
  __shared__ float ylds[128][65];
  __shared__ float wpl[9][64];
  int tid = threadIdx.x;
  for (int i = tid; i < 576; i += 128) {
    int c = i / 9, kk = i % 9;
    wpl[kk][c] = wpos[(size_t)l * 576 + i];
  }
  __syncthreads();
  int gpix = blockIdx.x * 128 + tid;
  int b = gpix >> 14;
  int p = gpix & 16383;
  int hh = p >> 7, ww = p & 127;
  const float* W2 = W2all + ((size_t)l * 16 + b) * 4096;
  const float* vr = v + (size_t)gpix * 64;
  const float* ar = actin + (size_t)gpix * 64;
  const float* bp = bproj + l * 64;
  float s1 = 0.f, s2 = 0.f;
#pragma unroll 1
  for (int jc = 0; jc < 4; jc++) {
    float acc[16];
#pragma unroll
    for (int j = 0; j < 16; j++) acc[j] = bp[jc * 16 + j];
#pragma unroll 1
    for (int cc = 0; cc < 4; cc++) {
      const float4 x0 = *(const float4*)(vr + cc * 16);
      const float4 x1 = *(const float4*)(vr + cc * 16 + 4);
      const float4 x2 = *(const float4*)(vr + cc * 16 + 8);
      const float4 x3 = *(const float4*)(vr + cc * 16 + 12);
      const float xv[16] = {x0.x,x0.y,x0.z,x0.w, x1.x,x1.y,x1.z,x1.w,
                            x2.x,x2.y,x2.z,x2.w, x3.x,x3.y,x3.z,x3.w};
#pragma unroll
      for (int ci = 0; ci < 16; ci++) {
        const float* wrow = W2 + (cc * 16 + ci) * 64 + jc * 16;
#pragma unroll
        for (int j = 0; j < 16; j++) acc[j] = fmaf(xv[ci], wrow[j], acc[j]);
      }
    }
    // depthwise 3x3 on v (zero-pad SAME)
    float op[16];
#pragma unroll
    for (int j = 0; j < 16; j++) op[j] = 0.f;
#pragma unroll 1
    for (int dy = -1; dy <= 1; dy++) {
#pragma unroll 1
      for (int dx = -1; dx <= 1; dx++) {
        bool ok = ((unsigned)(hh + dy) < 128u) && ((unsigned)(ww + dx) < 128u);
        const float* np = vr + (dy * NW + dx) * 64 + jc * 16;
        float4 n0 = {0,0,0,0}, n1 = {0,0,0,0}, n2 = {0,0,0,0}, n3 = {0,0,0,0};
        if (ok) {
          n0 = *(const float4*)(np);
          n1 = *(const float4*)(np + 4);
          n2 = *(const float4*)(np + 8);
          n3 = *(const float4*)(np + 12);
        }
        const float nv[16] = {n0.x,n0.y,n0.z,n0.w, n1.x,n1.y,n1.z,n1.w,
                              n2.x,n2.y,n2.z,n2.w, n3.x,n3.y,n3.z,n3.w};
        int kk = (dy + 1) * 3 + (dx + 1);
#pragma unroll
        for (int j = 0; j < 16; j++)
          op[j] = fmaf(nv[j], wpl[kk][jc * 16 + j], op[j]);
      }
    }
    const float4 a0 = *(const float4*)(ar + jc * 16);
    const float4 a1 = *(const float4*)(ar + jc * 16 + 4);
    const float4 a2 = *(const float4*)(ar + jc * 16 + 8);
    const float4 a3 = *(const float4*)(ar + jc * 16 + 12);
    const float av[16] = {a0.x,a0.y,a0.z,a0.w, a1.x,a1.y,a1.z,a1.w,
                          a2.x,a2.y,a2.z,a2.w, a3.x,a3.y,a3.z,a3.w};
#pragma unroll
    for (int j = 0; j < 16; j++) {
      float yv = acc[j] * op[j] + av[j];
      ylds[tid][jc * 16 + j] = yv;
      s1 += yv;
      s2 = fmaf(yv, yv, s2);
    }
  }
  // LayerNorm stats (biased, eps 1e-5)
  float m = s1 * (1.f / 64.f);
  float var = s2 * (1.f / 64.f) - m * m;
  float iv = 1.f / sqrtf(var + 1e-5f);
  const float* G = lng + l * 64;
  const float* Bb = lnb + l * 64;
  const float* WF = wff + (size_t)l * 4096;
  float* aout = actout + (size_t)gpix * 64;
#pragma unroll 1
  for (int jc = 0; jc < 4; jc++) {
    float acc[16];
#pragma unroll
    for (int j = 0; j < 16; j++) acc[j] = ylds[tid][jc * 16 + j];  // residual
#pragma unroll 1
    for (int cc = 0; cc < 4; cc++) {
#pragma unroll
      for (int ci = 0; ci < 16; ci++) {
        int cin = cc * 16 + ci;
        float yn = (ylds[tid][cin] - m) * iv * G[cin] + Bb[cin];
        const float* wrow = WF + cin * 64 + jc * 16;
#pragma unroll
        for (int j = 0; j < 16; j++) acc[j] = fmaf(yn, wrow[j], acc[j]);
      }
    }
    float4 o0 = {acc[0], acc[1], acc[2], acc[3]};
    float4 o1 = {acc[4], acc[5], acc[6], acc[7]};
    float4 o2 = {acc[8], acc[9], acc[10], acc[11]};
    float4 o3 = {acc[12], acc[13], acc[14], acc[15]};
    *(float4*)(aout + jc * 16)      = o0;
    *(float4*)(aout + jc * 16 + 4)  = o1;
    *(float4*)(aout + jc * 16 + 8)  = o2;
    *(float4*)(aout + jc * 16 + 12) = o3;
  }
}

// ---------------------------------------------------------------------------
// k4: per-channel sum & sumsq (optionally of leaky(x)) over channels-last buf
// ---------------------------------------------------------------------------
__global__ __launch_bounds__(256) void k_chanreduce(const float* __restrict__ in,
                                                    float* __restrict__ sums,
                                                    int mode) {
  int tid = threadIdx.x;
  int c = tid & 63;
  float s = 0.f, s2 = 0.f;
  size_t stride = (size_t)gridDim.x * blockDim.x;  // multiple of 64
  for (size_t idx = (size_t)blockIdx.x * blockDim.x + tid; idx < BUF; idx += stride) {
    float vv = in[idx];
    if (mode == 0) vv = leaky(vv);
    s += vv;
    s2 = fmaf(vv, vv, s2);
  }
  __shared__ float r1[256], r2[256];
  r1[tid] = s; r2[tid] = s2;
  __syncthreads();
  if (tid < 64) {
    s  = r1[tid] + r1[tid + 64] + r1[tid + 128] + r1[tid + 192];
    s2 = r2[tid] + r2[tid + 64] + r2[tid + 128] + r2[tid + 192];
    atomicAdd(&sums[c], s);
    atomicAdd(&sums[64 + c], s2);
  }
}

// k5: finalize BN -> per-channel scale a, shift b
__global__ __launch_bounds__(64) void k_bnfin(const float* __restrict__ sums,
                                              const float* __restrict__ g,
                                              const float* __restrict__ bt,
                                              float* __restrict__ ab, float eps) {
  int c = threadIdx.x;
  float m = sums[c] * (1.f / (float)NTOT);
  float v = sums[64 + c] * (1.f / (float)NTOT) - m * m;
  float a = g[c] / sqrtf(v + eps);
  ab[c] = a;
  ab[64 + c] = bt[c] - m * a;
}

// ---------------------------------------------------------------------------
// k6: lr2 = leaky( (a1*leaky(act)+b1) @ wd )
// ---------------------------------------------------------------------------
__global__ __launch_bounds__(256) void k_conv1x1(const float* __restrict__ act,
    const float* __restrict__ ab, const float* __restrict__ wd,
    float* __restrict__ out) {
  int gpix = blockIdx.x * 256 + threadIdx.x;
  const float* xr = act + (size_t)gpix * 64;
  float* o = out + (size_t)gpix * 64;
#pragma unroll 1
  for (int jc = 0; jc < 4; jc++) {
    float acc[16];
#pragma unroll
    for (int j = 0; j < 16; j++) acc[j] = 0.f;
#pragma unroll 1
    for (int cc = 0; cc < 4; cc++) {
      const float4 x0 = *(const float4*)(xr + cc * 16);
      const float4 x1 = *(const float4*)(xr + cc * 16 + 4);
      const float4 x2 = *(const float4*)(xr + cc * 16 + 8);
      const float4 x3 = *(const float4*)(xr + cc * 16 + 12);
      const float xv[16] = {x0.x,x0.y,x0.z,x0.w, x1.x,x1.y,x1.z,x1.w,
                            x2.x,x2.y,x2.z,x2.w, x3.x,x3.y,x3.z,x3.w};
#pragma unroll
      for (int ci = 0; ci < 16; ci++) {
        int cin = cc * 16 + ci;
        float t = fmaf(ab[cin], leaky(xv[ci]), ab[64 + cin]);
        const float* wrow = wd + cin * 64 + jc * 16;
#pragma unroll
        for (int j = 0; j < 16; j++) acc[j] = fmaf(t, wrow[j], acc[j]);
      }
    }
    float4 o0 = {leaky(acc[0]), leaky(acc[1]), leaky(acc[2]), leaky(acc[3])};
    float4 o1 = {leaky(acc[4]), leaky(acc[5]), leaky(acc[6]), leaky(acc[7])};
    float4 o2 = {leaky(acc[8]), leaky(acc[9]), leaky(acc[10]), leaky(acc[11])};
    float4 o3 = {leaky(acc[12]), leaky(acc[13]), leaky(acc[14]), leaky(acc[15])};
    *(float4*)(o + jc * 16)      = o0;
    *(float4*)(o + jc * 16 + 4)  = o1;
    *(float4*)(o + jc * 16 + 8)  = o2;
    *(float4*)(o + jc * 16 + 12) = o3;
  }
}

// ---------------------------------------------------------------------------
// k7: 8x8 pooled means of s = a2*lr2 + b2 + xA   -> y[b][c][64]
// block = (b, binrow, col-half); 512 threads
// ---------------------------------------------------------------------------
__global__ __launch_bounds__(512) void k_pool(const float* __restrict__ lr2,
    const float* __restrict__ xA, const float* __restrict__ ab2,
    float* __restrict__ y) {
  int blk = blockIdx.x;            // b*16 + br*2 + half
  int b = blk >> 4;
  int br = (blk >> 1) & 7;
  int half = blk & 1;
  int t = threadIdx.x;
  int c = t & 63;
  int w8 = t >> 6;                 // 0..7
  float a2 = ab2[c], b2 = ab2[64 + c];
  float acc[4];
#pragma unroll
  for (int i = 0; i < 4; i++) acc[i] = 0.f;
#pragma unroll 1
  for (int r = 0; r < 16; r++) {
    size_t base = ((size_t)(b * NPIX + (br * 16 + r) * NW + half * 64)) * 64;
#pragma unroll
    for (int i = 0; i < 8; i++) {
      size_t idx = base + (size_t)i * 512 + t;
      float sv = fmaf(a2, lr2[idx], b2) + xA[idx];
      acc[i >> 1] += sv;
    }
  }
  __shared__ float red[8][4][64];
#pragma unroll
  for (int i = 0; i < 4; i++) red[w8][i][c] = acc[i];
  __syncthreads();
  if (t < 256) {
    int bin = t >> 6, c2 = t & 63;
    float s = 0.f;
#pragma unroll
    for (int w = 0; w < 8; w++) s += red[w][bin][c2];
    y[((size_t)(b * 64 + c2)) * 64 + br * 8 + half * 4 + bin] = s * (1.f / 256.f);
  }
}

// ---------------------------------------------------------------------------
// k8: SAA tail: global min/max norm, correlation, SE-MLP -> gate[b][c]
// single block, 1024 threads
// ---------------------------------------------------------------------------
__global__ __launch_bounds__(1024) void k_saa(const float* __restrict__ y,
    const float* __restrict__ w1, const float* __restrict__ w2,
    float* __restrict__ gate) {
  int t = threadIdx.x;
  __shared__ float rmin[1024], rmax[1024];
  float mn = 1e30f, mx = -1e30f;
#pragma unroll 1
  for (int i = 0; i < 64; i++) {
    float vv = y[(size_t)i * 1024 + t];
    mn = fminf(mn, vv);
    mx = fmaxf(mx, vv);
  }
  rmin[t] = mn; rmax[t] = mx;
  __syncthreads();
  for (int s = 512; s > 0; s >>= 1) {
    if (t < s) {
      rmin[t] = fminf(rmin[t], rmin[t + s]);
      rmax[t] = fmaxf(rmax[t], rmax[t + s]);
    }
    __syncthreads();
  }
  float gmn = rmin[0], gmx = rmax[0];
  float inv = 1.f / (gmx - gmn);
  __syncthreads();
  int b = t >> 6;
  int i6 = t & 63;
  __shared__ float tl[16][64];
  {  // t[b][i] = sum_c yn[b][c][i]
    const float* yb = y + (size_t)b * 4096;
    float s = 0.f;
#pragma unroll 1
    for (int cl = 0; cl < 64; cl++) s += yb[cl * 64 + i6];
    tl[b][i6] = (s - 64.f * gmn) * inv;
  }
  __syncthreads();
  int cc = i6;
  const float* yc = y + (size_t)b * 4096 + cc * 64;
  float z = 0.f, ms = 0.f;
#pragma unroll 1
  for (int ii = 0; ii < 64; ii++) {
    float yr = yc[ii];
    z = fmaf((yr - gmn) * inv, tl[b][ii], z);
    ms += yr;
  }
  z *= (1.f / 64.f);
  ms *= (1.f / 64.f);
  __shared__ float g0l[16][64];
  g0l[b][cc] = z * ms;
  __syncthreads();
  __shared__ float hl[16][4];
  if (t < 64) {
    int bb = t >> 2, j = t & 3;
    float h = 0.f;
#pragma unroll 1
    for (int c2 = 0; c2 < 64; c2++) h = fmaf(g0l[bb][c2], w1[c2 * 4 + j], h);
    hl[bb][j] = leaky(h);
  }
  __syncthreads();
  float acc = 0.f;
#pragma unroll
  for (int j = 0; j < 4; j++) acc = fmaf(hl[b][j], w2[j * 64 + cc], acc);
  gate[t] = 1.f / (1.f + expf(-acc));
}

// ---------------------------------------------------------------------------
// k9: out[b][c][p] = (a2*lr2 + b2 + xA) * gate[b][c]  (channels-last -> NCHW)
// ---------------------------------------------------------------------------
__global__ __launch_bounds__(256) void k_out(const float* __restrict__ lr2,
    const float* __restrict__ xA, const float* __restrict__ ab2,
    const float* __restrict__ gate, float* __restrict__ out) {
  __shared__ float tile[64][65];
  int blk = blockIdx.x;            // b*256 + seg
  int b = blk >> 8;
  int p0 = (blk & 255) * 64;
  int tid = threadIdx.x;
  int c = tid & 63, pq = tid >> 6;
  float a2 = ab2[c], b2 = ab2[64 + c];
  for (int i = 0; i < 16; i++) {
    int p = pq * 16 + i;
    size_t idx = ((size_t)(b * NPIX + p0 + p)) * 64 + c;
    tile[p][c] = fmaf(a2, lr2[idx], b2) + xA[idx];
  }
  __syncthreads();
  int p = tid & 63, cq = tid >> 6;
  for (int i = 0; i < 16; i++) {
    int c2 = cq * 16 + i;
    out[((size_t)(b * 64 + c2)) * NPIX + p0 + p] = tile[p][c2] * gate[b * 64 + c2];
  }
}

// ---------------------------------------------------------------------------
extern "C" void kernel_launch(void* const* d_in, const int* in_sizes, int n_in,
                              void* d_out, int out_size, void* d_ws, size_t ws_size,
                              hipStream_t stream) {
  const float* x     = (const float*)d_in[0];
  const float* wq    = (const float*)d_in[1];
  const float* wk    = (const float*)d_in[2];
  const float* wv    = (const float*)d_in[3];
  const float* wproj = (const float*)d_in[4];
  const float* bproj = (const float*)d_in[5];
  const float* wpos  = (const float*)d_in[6];
  const float* ln_g  = (const float*)d_in[7];
  const float* ln_b  = (const float*)d_in[8];
  const float* wff   = (const float*)d_in[9];
  const float* bn1_g = (const float*)d_in[10];
  const float* bn1_b = (const float*)d_in[11];
  const float* wd    = (const float*)d_in[12];
  const float* bn2_g = (const float*)d_in[13];
  const float* bn2_b = (const float*)d_in[14];
  const float* sw1   = (const float*)d_in[15];
  const float* sw2   = (const float*)d_in[16];

  float* ws   = (float*)d_ws;
  float* A    = ws + OFF_A;
  float* ACT  = ws + OFF_ACT;
  float* V    = ws + OFF_V;
  float* S    = ws + OFF_S;
  float* QSQ  = ws + OFF_QSQ;
  float* KSQ  = ws + OFF_KSQ;
  float* BN1S = ws + OFF_BN1;
  float* BN2S = ws + OFF_BN2;
  float* W2   = ws + OFF_W2;
  float* AB1  = ws + OFF_AB1;
  float* AB2  = ws + OFF_AB2;
  float* Y    = ws + OFF_Y;
  float* GATE = ws + OFF_GATE;

  // zero the atomic accumulators (ws is poisoned before every call)
  hipMemsetAsync((void*)S, 0, ZERO_FLOATS * sizeof(float), stream);

  k_transpose_in<<<4096, 256, 0, stream>>>(x, A);

  for (int l = 0; l < 2; l++) {
    const float* in = (l == 0) ? A : ACT;
    k_mat_v<<<NTOT / 256, 256, 0, stream>>>(in, wv, V, l);
    k_qk_stats<<<512, 256, 0, stream>>>(in, wq, wk, S, QSQ, KSQ, l);
    k_attn<<<16, 64, 0, stream>>>(S, QSQ, KSQ, wproj, W2, l);
    k_attnout_ff<<<NTOT / 128, 128, 0, stream>>>(V, in, ACT, W2, bproj, wpos,
                                                 ln_g, ln_b, wff, l);
  }

  k_chanreduce<<<512, 256, 0, stream>>>(ACT, BN1S, 0);
  k_bnfin<<<1, 64, 0, stream>>>(BN1S, bn1_g, bn1_b, AB1, 1e-4f);
  k_conv1x1<<<NTOT / 256, 256, 0, stream>>>(ACT, AB1, wd, V);  // V := lr2
  k_chanreduce<<<512, 256, 0, stream>>>(V, BN2S, 1);
  k_bnfin<<<1, 64, 0, stream>>>(BN2S, bn2_g, bn2_b, AB2, 1e-4f);
  k_pool<<<256, 512, 0, stream>>>(V, A, AB2, Y);
  k_saa<<<1, 1024, 0, stream>>>(Y, sw1, sw2, GATE);
  k_out<<<4096, 256, 0, stream>>>(V, A, AB2, GATE, (float*)d_out);
}

// Round 3
// 1321.377 us; speedup vs baseline: 1.1461x; 1.1461x over previous
//
#include <hip/hip_runtime.h>

// ---------------------------------------------------------------------------
// Problem geometry
// ---------------------------------------------------------------------------
constexpr int NB = 16, NC = 64, NH = 128, NW = 128;
constexpr int NPIX = NH * NW;          // 16384
constexpr int NTOT = NB * NPIX;        // 262144 pixels
constexpr size_t BUF = (size_t)NTOT * NC;  // 16,777,216 floats = 64 MB

// ws layout (float offsets)
constexpr size_t OFF_A   = 0;                    // x channels-last (pristine)
constexpr size_t OFF_ACT = BUF;                  // running activation
constexpr size_t OFF_V   = 2 * BUF;              // v, later lr2
constexpr size_t OFF_S   = 3 * BUF;              // [2][16][8][8][8] = 16384
constexpr size_t OFF_QSQ = OFF_S   + 2*16*512;   // [2][16][64] = 2048
constexpr size_t OFF_KSQ = OFF_QSQ + 2048;       // 2048
constexpr size_t OFF_BN1 = OFF_KSQ + 2048;       // sum[64], sumsq[64]
constexpr size_t OFF_BN2 = OFF_BN1 + 128;        // 128
constexpr size_t ZERO_FLOATS = 16384 + 2048 + 2048 + 128 + 128; // 20736
constexpr size_t OFF_W2  = OFF_BN2 + 128;        // [2][16][64][64] = 131072
constexpr size_t OFF_AB1 = OFF_W2  + 131072;     // a1[64], b1[64]
constexpr size_t OFF_AB2 = OFF_AB1 + 128;        // a2[64], b2[64]
constexpr size_t OFF_Y   = OFF_AB2 + 128;        // [16][64][64] = 65536
constexpr size_t OFF_GATE= OFF_Y   + 65536;      // [16][64]

__device__ __forceinline__ float leaky(float x) { return x >= 0.f ? x : 0.2f * x; }
#define RFL __builtin_amdgcn_readfirstlane

// ---------------------------------------------------------------------------
// k0: NCHW -> channels-last (BHWC)
// ---------------------------------------------------------------------------
__global__ __launch_bounds__(256) void k_transpose_in(const float* __restrict__ x,
                                                      float* __restrict__ A) {
  __shared__ float t[64][65];
  int blk = blockIdx.x;            // b*256 + seg
  int b = blk >> 8;
  int p0 = (blk & 255) * 64;
  int tid = threadIdx.x;
  int cq = tid >> 6, p = tid & 63;
  for (int i = 0; i < 16; i++) {
    int c = cq * 16 + i;
    t[p][c] = x[((size_t)(b * 64 + c)) * NPIX + p0 + p];
  }
  __syncthreads();
  int pq = tid >> 6, c = tid & 63;
  for (int i = 0; i < 16; i++) {
    int p2 = pq * 16 + i;
    A[((size_t)(b * NPIX + p0 + p2)) * 64 + c] = t[p2][c];
  }
}

// ---------------------------------------------------------------------------
// k1: fused q,k,v. Wave = 64 consecutive pixels; lane = output channel.
// Weight columns wq/wk/wv[:,lane] in VGPRs. Activation row broadcast via
// LDS bounce (1 coalesced load + 16 uniform ds_read_b128 = conflict-free
// broadcast). Accumulates S[b,h,d,e], sum q^2, sum k^2; writes v.
// ---------------------------------------------------------------------------
__global__ __launch_bounds__(256, 2) void k_qkv(const float* __restrict__ act,
    const float* __restrict__ wq, const float* __restrict__ wk,
    const float* __restrict__ wv, float* __restrict__ v,
    float* __restrict__ S, float* __restrict__ qsq, float* __restrict__ ksq,
    int l) {
  __shared__ float xb[8][64];
  int tid = threadIdx.x;
  int lane = tid & 63;
  int wid = RFL((int)(blockIdx.x * 4 + (tid >> 6)));   // 0..4095 (uniform)
  int wslot = wid & 3;
  int b = wid >> 8;
  const float* Wq = wq + (size_t)l * 4096;
  const float* Wk = wk + (size_t)l * 4096;
  const float* Wv = wv + (size_t)l * 4096;
  float wqc[64], wkc[64], wvc[64];
#pragma unroll
  for (int ci = 0; ci < 64; ci++) {
    wqc[ci] = Wq[ci * 64 + lane];
    wkc[ci] = Wk[ci * 64 + lane];
    wvc[ci] = Wv[ci * 64 + lane];
  }
  float Sacc[8];
#pragma unroll
  for (int e = 0; e < 8; e++) Sacc[e] = 0.f;
  float qsa = 0.f, ksa = 0.f;
  int gbase = lane & 56;
  int base = wid * 4096;           // float offset of first pixel row
#pragma unroll 1
  for (int p = 0; p < 64; p++) {
    int off = base + p * 64;
    float xl = act[off + lane];    // coalesced: lane = input channel
    int xs = wslot * 2 + (p & 1);  // parity double-buffer (WAR safety)
    xb[xs][lane] = xl;
    const float4* x4p = (const float4*)xb[xs];
    float q = 0.f, k = 0.f, vv = 0.f;
#pragma unroll
    for (int i = 0; i < 16; i++) {
      float4 x4 = x4p[i];          // uniform addr -> broadcast ds_read_b128
      q  = fmaf(x4.x, wqc[4*i+0], q);
      k  = fmaf(x4.x, wkc[4*i+0], k);
      vv = fmaf(x4.x, wvc[4*i+0], vv);
      q  = fmaf(x4.y, wqc[4*i+1], q);
      k  = fmaf(x4.y, wkc[4*i+1], k);
      vv = fmaf(x4.y, wvc[4*i+1], vv);
      q  = fmaf(x4.z, wqc[4*i+2], q);
      k  = fmaf(x4.z, wkc[4*i+2], k);
      vv = fmaf(x4.z, wvc[4*i+2], vv);
      q  = fmaf(x4.w, wqc[4*i+3], q);
      k  = fmaf(x4.w, wkc[4*i+3], k);
      vv = fmaf(x4.w, wvc[4*i+3], vv);
    }
    qsa = fmaf(q, q, qsa);
    ksa = fmaf(k, k, ksa);
#pragma unroll
    for (int e = 0; e < 8; e++) {
      float qe = __shfl(q, gbase + e, 64);
      Sacc[e] = fmaf(k, qe, Sacc[e]);
    }
    v[off + lane] = vv;
  }
  float* Sb = S + ((size_t)l * 16 + b) * 512 + lane * 8;  // lane = h*8+d
#pragma unroll
  for (int e = 0; e < 8; e++) atomicAdd(Sb + e, Sacc[e]);
  atomicAdd(qsq + ((size_t)l * 16 + b) * 64 + lane, qsa);
  atomicAdd(ksq + ((size_t)l * 16 + b) * 64 + lane, ksa);
}

// ---------------------------------------------------------------------------
// k2: per-batch attention softmax (8x8 per head) -> fold with wproj into W2
// ---------------------------------------------------------------------------
__global__ __launch_bounds__(64) void k_attn(const float* __restrict__ S,
    const float* __restrict__ qsq, const float* __restrict__ ksq,
    const float* __restrict__ wproj, float* __restrict__ W2, int l) {
  int b = blockIdx.x, t = threadIdx.x;
  __shared__ float A[8][8][8];  // [h][d][e]
  const float* Sb = S + ((size_t)l * 16 + b) * 512;
  const float* qs = qsq + ((size_t)l * 16 + b) * 64;
  const float* ks = ksq + ((size_t)l * 16 + b) * 64;
  int h = t >> 3, d = t & 7;
  float kden = fmaxf(sqrtf(ks[h * 8 + d]), 1e-12f);
  float pre[8];
  float mx = -1e30f;
#pragma unroll
  for (int e = 0; e < 8; e++) {
    float qden = fmaxf(sqrtf(qs[h * 8 + e]), 1e-12f);
    pre[e] = Sb[(h * 8 + d) * 8 + e] / (kden * qden);
    mx = fmaxf(mx, pre[e]);
  }
  float sum = 0.f;
#pragma unroll
  for (int e = 0; e < 8; e++) { pre[e] = expf(pre[e] - mx); sum += pre[e]; }
  float inv = 1.f / sum;
#pragma unroll
  for (int e = 0; e < 8; e++) A[h][d][e] = pre[e] * inv;
  __syncthreads();
  int co = t;
  const float* wp = wproj + (size_t)l * 4096;
  float* W2b = W2 + ((size_t)l * 16 + b) * 4096;
#pragma unroll 1
  for (int cin = 0; cin < 64; cin++) {
    int hh2 = cin >> 3, e = cin & 7;
    float acc = 0.f;
#pragma unroll
    for (int dd = 0; dd < 8; dd++)
      acc = fmaf(A[hh2][dd][e], wp[(hh2 * 8 + dd) * 64 + co], acc);
    W2b[cin * 64 + co] = acc;
  }
}

// ---------------------------------------------------------------------------
// k3: y = (v@W2 + bproj) * dw3x3(v) + act ; LN(y) @ wff + y -> actout
// Wave = 64 consecutive pixels (half an image row); lane = channel.
// W2/WF columns in VGPRs; 3x3 window slides in registers (3 loads/pixel);
// LN via shfl_xor tree; broadcasts via per-wave LDS slots.
// Optionally accumulates BN1 sums of leaky(out).
// ---------------------------------------------------------------------------
__global__ __launch_bounds__(256, 2) void k_attnout_ff(
    const float* __restrict__ vbuf, const float* __restrict__ actin,
    float* __restrict__ actout, const float* __restrict__ W2all,
    const float* __restrict__ bproj, const float* __restrict__ wpos,
    const float* __restrict__ lng, const float* __restrict__ lnb,
    const float* __restrict__ wff, float* __restrict__ bn1, int l, int dobn) {
  __shared__ float xb[8][64], yb[8][64];
  int tid = threadIdx.x;
  int lane = tid & 63;
  // XCD-chunked swizzle: 1024 blocks, 8 XCDs, 128 contiguous blocks each.
  int bid = blockIdx.x;
  int sbid = (bid & 7) * 128 + (bid >> 3);
  int wid = RFL((int)(sbid * 4 + (tid >> 6)));   // 0..4095 (uniform)
  int wslot = wid & 3;
  int b = wid >> 8;
  int widb = wid & 255;
  int hh = widb >> 1;          // image row
  int c0 = (widb & 1) * 64;    // starting column
  const float* W2 = W2all + ((size_t)l * 16 + b) * 4096;
  const float* WF = wff + (size_t)l * 4096;
  float w2c[64], wfc[64];
#pragma unroll
  for (int ci = 0; ci < 64; ci++) {
    w2c[ci] = W2[ci * 64 + lane];
    wfc[ci] = WF[ci * 64 + lane];
  }
  float wpc[9];
#pragma unroll
  for (int kk = 0; kk < 9; kk++) wpc[kk] = wpos[(size_t)l * 576 + lane * 9 + kk];
  float bp = bproj[l * 64 + lane];
  float G  = lng[l * 64 + lane];
  float Bb = lnb[l * 64 + lane];

  bool okm = (hh > 0), okp = (hh < 127);
  int base = wid * 4096;
  // sliding 3x3 window: L = col-1, C = col, R = col+1 (rows -1,0,+1)
  float Lm = 0.f, L0 = 0.f, Lp = 0.f, Cm = 0.f, C0, Cp = 0.f;
  C0 = vbuf[base + lane];
  if (okm) Cm = vbuf[base - 8192 + lane];
  if (okp) Cp = vbuf[base + 8192 + lane];
  if (c0 == 64) {
    L0 = vbuf[base - 64 + lane];
    if (okm) Lm = vbuf[base - 64 - 8192 + lane];
    if (okp) Lp = vbuf[base - 64 + 8192 + lane];
  }
  float s_bn = 0.f, s2_bn = 0.f;
#pragma unroll 1
  for (int p = 0; p < 64; p++) {
    int off = base + p * 64;
    // load next column (col+1)
    float Rm = 0.f, R0 = 0.f, Rp = 0.f;
    bool okc = (c0 + p + 1 < 128);
    if (okc) {
      R0 = vbuf[off + 64 + lane];
      if (okm) Rm = vbuf[off + 64 - 8192 + lane];
      if (okp) Rp = vbuf[off + 64 + 8192 + lane];
    }
    // broadcast v row via LDS
    int xs = wslot * 2 + (p & 1);
    xb[xs][lane] = C0;
    const float4* x4p = (const float4*)xb[xs];
    float a0 = 0.f, a1 = 0.f, a2 = 0.f, a3 = 0.f;
#pragma unroll
    for (int i = 0; i < 16; i++) {
      float4 x4 = x4p[i];
      a0 = fmaf(x4.x, w2c[4*i+0], a0);
      a1 = fmaf(x4.y, w2c[4*i+1], a1);
      a2 = fmaf(x4.z, w2c[4*i+2], a2);
      a3 = fmaf(x4.w, w2c[4*i+3], a3);
    }
    float acc = (a0 + a1) + (a2 + a3) + bp;
    // depthwise 3x3
    float op = Lm * wpc[0] + Cm * wpc[1] + Rm * wpc[2]
             + L0 * wpc[3] + C0 * wpc[4] + R0 * wpc[5]
             + Lp * wpc[6] + Cp * wpc[7] + Rp * wpc[8];
    float av = actin[off + lane];
    float y = acc * op + av;
    // LayerNorm stats across 64 lanes
    float t1 = y, t2 = y * y;
#pragma unroll
    for (int m = 1; m < 64; m <<= 1) {
      t1 += __shfl_xor(t1, m, 64);
      t2 += __shfl_xor(t2, m, 64);
    }
    float mean = t1 * (1.f / 64.f);
    float var = t2 * (1.f / 64.f) - mean * mean;
    float iv = 1.f / sqrtf(var + 1e-5f);
    float yn = (y - mean) * iv * G + Bb;
    // broadcast yn via LDS, second matvec
    yb[xs][lane] = yn;
    const float4* y4p = (const float4*)yb[xs];
    float o0 = 0.f, o1 = 0.f, o2 = 0.f, o3 = 0.f;
#pragma unroll
    for (int i = 0; i < 16; i++) {
      float4 y4 = y4p[i];
      o0 = fmaf(y4.x, wfc[4*i+0], o0);
      o1 = fmaf(y4.y, wfc[4*i+1], o1);
      o2 = fmaf(y4.z, wfc[4*i+2], o2);
      o3 = fmaf(y4.w, wfc[4*i+3], o3);
    }
    float out = y + (o0 + o1) + (o2 + o3);
    if (dobn) {
      float lo = leaky(out);
      s_bn += lo;
      s2_bn = fmaf(lo, lo, s2_bn);
    }
    actout[off + lane] = out;
    // slide window
    Lm = Cm; L0 = C0; Lp = Cp;
    Cm = Rm; C0 = R0; Cp = Rp;
  }
  if (dobn) {
    atomicAdd(&bn1[lane], s_bn);
    atomicAdd(&bn1[64 + lane], s2_bn);
  }
}

// k5: finalize BN -> per-channel scale a, shift b
__global__ __launch_bounds__(64) void k_bnfin(const float* __restrict__ sums,
                                              const float* __restrict__ g,
                                              const float* __restrict__ bt,
                                              float* __restrict__ ab, float eps) {
  int c = threadIdx.x;
  float m = sums[c] * (1.f / (float)NTOT);
  float v = sums[64 + c] * (1.f / (float)NTOT) - m * m;
  float a = g[c] / sqrtf(v + eps);
  ab[c] = a;
  ab[64 + c] = bt[c] - m * a;
}

// ---------------------------------------------------------------------------
// k6: lr2 = leaky( (a1*leaky(act)+b1) @ wd ), fused BN2 sum/sumsq accumulate
// ---------------------------------------------------------------------------
__global__ __launch_bounds__(256, 4) void k_conv1x1(const float* __restrict__ act,
    const float* __restrict__ ab, const float* __restrict__ wd,
    float* __restrict__ outv, float* __restrict__ bn2) {
  __shared__ float xb[8][64];
  int tid = threadIdx.x;
  int lane = tid & 63;
  int wid = RFL((int)(blockIdx.x * 4 + (tid >> 6)));
  int wslot = wid & 3;
  float wdc[64];
#pragma unroll
  for (int ci = 0; ci < 64; ci++) wdc[ci] = wd[ci * 64 + lane];
  float a1l = ab[lane], b1l = ab[64 + lane];
  float s_bn = 0.f, s2_bn = 0.f;
  int base = wid * 4096;
#pragma unroll 1
  for (int p = 0; p < 64; p++) {
    int off = base + p * 64;
    float xl = act[off + lane];
    float tl = fmaf(a1l, leaky(xl), b1l);
    int xs = wslot * 2 + (p & 1);
    xb[xs][lane] = tl;
    const float4* x4p = (const float4*)xb[xs];
    float a0 = 0.f, a1 = 0.f, a2 = 0.f, a3 = 0.f;
#pragma unroll
    for (int i = 0; i < 16; i++) {
      float4 x4 = x4p[i];
      a0 = fmaf(x4.x, wdc[4*i+0], a0);
      a1 = fmaf(x4.y, wdc[4*i+1], a1);
      a2 = fmaf(x4.z, wdc[4*i+2], a2);
      a3 = fmaf(x4.w, wdc[4*i+3], a3);
    }
    float out = leaky((a0 + a1) + (a2 + a3));
    s_bn += out;
    s2_bn = fmaf(out, out, s2_bn);
    outv[off + lane] = out;
  }
  atomicAdd(&bn2[lane], s_bn);
  atomicAdd(&bn2[64 + lane], s2_bn);
}

// ---------------------------------------------------------------------------
// k7: 8x8 pooled means of s = a2*lr2 + b2 + xA   -> y[b][c][64]
// ---------------------------------------------------------------------------
__global__ __launch_bounds__(512) void k_pool(const float* __restrict__ lr2,
    const float* __restrict__ xA, const float* __restrict__ ab2,
    float* __restrict__ y) {
  int blk = blockIdx.x;            // b*16 + br*2 + half
  int b = blk >> 4;
  int br = (blk >> 1) & 7;
  int half = blk & 1;
  int t = threadIdx.x;
  int c = t & 63;
  int w8 = t >> 6;                 // 0..7
  float a2 = ab2[c], b2 = ab2[64 + c];
  float acc[4];
#pragma unroll
  for (int i = 0; i < 4; i++) acc[i] = 0.f;
#pragma unroll 1
  for (int r = 0; r < 16; r++) {
    size_t base = ((size_t)(b * NPIX + (br * 16 + r) * NW + half * 64)) * 64;
#pragma unroll
    for (int i = 0; i < 8; i++) {
      size_t idx = base + (size_t)i * 512 + t;
      float sv = fmaf(a2, lr2[idx], b2) + xA[idx];
      acc[i >> 1] += sv;
    }
  }
  __shared__ float red[8][4][64];
#pragma unroll
  for (int i = 0; i < 4; i++) red[w8][i][c] = acc[i];
  __syncthreads();
  if (t < 256) {
    int bin = t >> 6, c2 = t & 63;
    float s = 0.f;
#pragma unroll
    for (int w = 0; w < 8; w++) s += red[w][bin][c2];
    y[((size_t)(b * 64 + c2)) * 64 + br * 8 + half * 4 + bin] = s * (1.f / 256.f);
  }
}

// ---------------------------------------------------------------------------
// k8: SAA tail: global min/max norm, correlation, SE-MLP -> gate[b][c]
// ---------------------------------------------------------------------------
__global__ __launch_bounds__(1024) void k_saa(const float* __restrict__ y,
    const float* __restrict__ w1, const float* __restrict__ w2,
    float* __restrict__ gate) {
  int t = threadIdx.x;
  __shared__ float rmin[1024], rmax[1024];
  float mn = 1e30f, mx = -1e30f;
#pragma unroll 1
  for (int i = 0; i < 64; i++) {
    float vv = y[(size_t)i * 1024 + t];
    mn = fminf(mn, vv);
    mx = fmaxf(mx, vv);
  }
  rmin[t] = mn; rmax[t] = mx;
  __syncthreads();
  for (int s = 512; s > 0; s >>= 1) {
    if (t < s) {
      rmin[t] = fminf(rmin[t], rmin[t + s]);
      rmax[t] = fmaxf(rmax[t], rmax[t + s]);
    }
    __syncthreads();
  }
  float gmn = rmin[0], gmx = rmax[0];
  float inv = 1.f / (gmx - gmn);
  __syncthreads();
  int b = t >> 6;
  int i6 = t & 63;
  __shared__ float tl[16][64];
  {  // t[b][i] = sum_c yn[b][c][i]
    const float* yb2 = y + (size_t)b * 4096;
    float s = 0.f;
#pragma unroll 1
    for (int cl = 0; cl < 64; cl++) s += yb2[cl * 64 + i6];
    tl[b][i6] = (s - 64.f * gmn) * inv;
  }
  __syncthreads();
  int cc = i6;
  const float* yc = y + (size_t)b * 4096 + cc * 64;
  float z = 0.f, ms = 0.f;
#pragma unroll 1
  for (int ii = 0; ii < 64; ii++) {
    float yr = yc[ii];
    z = fmaf((yr - gmn) * inv, tl[b][ii], z);
    ms += yr;
  }
  z *= (1.f / 64.f);
  ms *= (1.f / 64.f);
  __shared__ float g0l[16][64];
  g0l[b][cc] = z * ms;
  __syncthreads();
  __shared__ float hl[16][4];
  if (t < 64) {
    int bb = t >> 2, j = t & 3;
    float h = 0.f;
#pragma unroll 1
    for (int c2 = 0; c2 < 64; c2++) h = fmaf(g0l[bb][c2], w1[c2 * 4 + j], h);
    hl[bb][j] = leaky(h);
  }
  __syncthreads();
  float acc = 0.f;
#pragma unroll
  for (int j = 0; j < 4; j++) acc = fmaf(hl[b][j], w2[j * 64 + cc], acc);
  gate[t] = 1.f / (1.f + expf(-acc));
}

// ---------------------------------------------------------------------------
// k9: out[b][c][p] = (a2*lr2 + b2 + xA) * gate[b][c]  (channels-last -> NCHW)
// ---------------------------------------------------------------------------
__global__ __launch_bounds__(256) void k_out(const float* __restrict__ lr2,
    const float* __restrict__ xA, const float* __restrict__ ab2,
    const float* __restrict__ gate, float* __restrict__ out) {
  __shared__ float tile[64][65];
  int blk = blockIdx.x;            // b*256 + seg
  int b = blk >> 8;
  int p0 = (blk & 255) * 64;
  int tid = threadIdx.x;
  int c = tid & 63, pq = tid >> 6;
  float a2 = ab2[c], b2 = ab2[64 + c];
  for (int i = 0; i < 16; i++) {
    int p = pq * 16 + i;
    size_t idx = ((size_t)(b * NPIX + p0 + p)) * 64 + c;
    tile[p][c] = fmaf(a2, lr2[idx], b2) + xA[idx];
  }
  __syncthreads();
  int p = tid & 63, cq = tid >> 6;
  for (int i = 0; i < 16; i++) {
    int c2 = cq * 16 + i;
    out[((size_t)(b * 64 + c2)) * NPIX + p0 + p] = tile[p][c2] * gate[b * 64 + c2];
  }
}

// ---------------------------------------------------------------------------
extern "C" void kernel_launch(void* const* d_in, const int* in_sizes, int n_in,
                              void* d_out, int out_size, void* d_ws, size_t ws_size,
                              hipStream_t stream) {
  const float* x     = (const float*)d_in[0];
  const float* wq    = (const float*)d_in[1];
  const float* wk    = (const float*)d_in[2];
  const float* wv    = (const float*)d_in[3];
  const float* wproj = (const float*)d_in[4];
  const float* bproj = (const float*)d_in[5];
  const float* wpos  = (const float*)d_in[6];
  const float* ln_g  = (const float*)d_in[7];
  const float* ln_b  = (const float*)d_in[8];
  const float* wff   = (const float*)d_in[9];
  const float* bn1_g = (const float*)d_in[10];
  const float* bn1_b = (const float*)d_in[11];
  const float* wd    = (const float*)d_in[12];
  const float* bn2_g = (const float*)d_in[13];
  const float* bn2_b = (const float*)d_in[14];
  const float* sw1   = (const float*)d_in[15];
  const float* sw2   = (const float*)d_in[16];

  float* ws   = (float*)d_ws;
  float* A    = ws + OFF_A;
  float* ACT  = ws + OFF_ACT;
  float* V    = ws + OFF_V;
  float* S    = ws + OFF_S;
  float* QSQ  = ws + OFF_QSQ;
  float* KSQ  = ws + OFF_KSQ;
  float* BN1S = ws + OFF_BN1;
  float* BN2S = ws + OFF_BN2;
  float* W2   = ws + OFF_W2;
  float* AB1  = ws + OFF_AB1;
  float* AB2  = ws + OFF_AB2;
  float* Y    = ws + OFF_Y;
  float* GATE = ws + OFF_GATE;

  // zero the atomic accumulators (ws is poisoned before every call)
  hipMemsetAsync((void*)S, 0, ZERO_FLOATS * sizeof(float), stream);

  k_transpose_in<<<4096, 256, 0, stream>>>(x, A);

  for (int l = 0; l < 2; l++) {
    const float* in = (l == 0) ? A : ACT;
    k_qkv<<<1024, 256, 0, stream>>>(in, wq, wk, wv, V, S, QSQ, KSQ, l);
    k_attn<<<16, 64, 0, stream>>>(S, QSQ, KSQ, wproj, W2, l);
    k_attnout_ff<<<1024, 256, 0, stream>>>(V, in, ACT, W2, bproj, wpos,
                                           ln_g, ln_b, wff, BN1S, l, l == 1);
  }

  k_bnfin<<<1, 64, 0, stream>>>(BN1S, bn1_g, bn1_b, AB1, 1e-4f);
  k_conv1x1<<<1024, 256, 0, stream>>>(ACT, AB1, wd, V, BN2S);
  k_bnfin<<<1, 64, 0, stream>>>(BN2S, bn2_g, bn2_b, AB2, 1e-4f);
  k_pool<<<256, 512, 0, stream>>>(V, A, AB2, Y);
  k_saa<<<1, 1024, 0, stream>>>(Y, sw1, sw2, GATE);
  k_out<<<4096, 256, 0, stream>>>(V, A, AB2, GATE, (float*)d_out);
}